// Round 2
// baseline (2998.688 us; speedup 1.0000x reference)
//
#include <hip/hip_runtime.h>

#define NPTS 1000000
#define NVOX 200000
#define EPSV 1e-5f

// ws layout (floats):
// [0, 800000)            vox_sum: per-voxel {sum_x, sum_y, sum_z, count}
// [800000, +13)          sumF   (col sums of 13 features)
// [800013, +91)          M2     (upper-tri second moments, 13x13)
// [800104, +832)         Wf     (folded BN0+w1+BN1, 13x64)
// [800936, +64)          bf     (folded bias)
// [801000, +64)          sumH   (col sums of h2)
// [801064, +64)          sumQ   (col sums of h2^2)
// [801128, +64)          s2     (BN2 scale)
// [801192, +64)          t2     (BN2 shift)
#define OFF_SUMF 800000
#define OFF_M2   800013
#define OFF_WF   800104
#define OFF_BF   800936
#define OFF_SUMH 801000
#define OFF_SUMQ 801064
#define OFF_S2   801128
#define OFF_T2   801192
#define WS_FLOATS 801256

__device__ __forceinline__ float bcast(float x, int k) {
    return __int_as_float(__builtin_amdgcn_readlane(__float_as_int(x), k));
}

// ---------------- K1: scatter xyz sums + counts per voxel ----------------
__global__ __launch_bounds__(256) void k1_scatter_xyz(
    const float4* __restrict__ pts, const int* __restrict__ cinv,
    float* __restrict__ vox)
{
    int i = blockIdx.x * blockDim.x + threadIdx.x;
    if (i >= NPTS) return;
    float4 p = pts[i];
    int v = cinv[i];
    atomicAdd(&vox[v * 4 + 0], p.x);
    atomicAdd(&vox[v * 4 + 1], p.y);
    atomicAdd(&vox[v * 4 + 2], p.z);
    atomicAdd(&vox[v * 4 + 3], 1.0f);
}

// ---------------- K2: first/second moments of the 13 features ----------------
// __launch_bounds__(256,2): cap 256 VGPR/lane so the 104 accumulators stay in
// registers (R1 profile: bare bound gave 76 VGPRs -> full spill, 578us @1% VALU).
__global__ __launch_bounds__(256, 2) void k2_stats0(
    const float4* __restrict__ pts, const float* __restrict__ nor,
    const int* __restrict__ gind, const int* __restrict__ cinv,
    const float4* __restrict__ vox4,
    float* __restrict__ sumF, float* __restrict__ M2)
{
    int tid = blockIdx.x * blockDim.x + threadIdx.x;
    int T = gridDim.x * blockDim.x;
    float sf[13];
    float m2[91];
#pragma unroll
    for (int j = 0; j < 13; j++) sf[j] = 0.f;
#pragma unroll
    for (int j = 0; j < 91; j++) m2[j] = 0.f;

    for (int i = tid; i < NPTS; i += T) {
        float4 p = pts[i];
        int v = cinv[i];
        float4 vs = vox4[v];
        float ic = 1.0f / fmaxf(vs.w, 1.0f);
        float gx = (float)gind[3 * i + 0];
        float gy = (float)gind[3 * i + 1];
        float gz = (float)gind[3 * i + 2];
        float f[13];
        f[0] = p.x; f[1] = p.y; f[2] = p.z; f[3] = p.w;
        f[4] = p.x - vs.x * ic;
        f[5] = p.y - vs.y * ic;
        f[6] = p.z - vs.z * ic;
        f[7] = p.x - (gx * 0.2f - 51.2f);
        f[8] = p.y - (gy * 0.2f - 51.2f);
        f[9] = p.z - (gz * 0.2f - 4.0f);
        f[10] = nor[3 * i + 0]; f[11] = nor[3 * i + 1]; f[12] = nor[3 * i + 2];
#pragma unroll
        for (int j = 0; j < 13; j++) sf[j] += f[j];
        int idx = 0;
#pragma unroll
        for (int j = 0; j < 13; j++)
#pragma unroll
            for (int l = j; l < 13; l++) { m2[idx] += f[j] * f[l]; idx++; }
    }

    int lane = threadIdx.x & 63;
#pragma unroll
    for (int j = 0; j < 13; j++) {
        float x = sf[j];
        for (int o = 32; o > 0; o >>= 1) x += __shfl_down(x, o);
        if (lane == 0) atomicAdd(&sumF[j], x);
    }
#pragma unroll
    for (int j = 0; j < 91; j++) {
        float x = m2[j];
        for (int o = 32; o > 0; o >>= 1) x += __shfl_down(x, o);
        if (lane == 0) atomicAdd(&M2[j], x);
    }
}

// ---------------- K3: fold BN0 + w1 + BN1 into Wf, bf ----------------
__global__ void k3_fold(
    const float* __restrict__ sumF, const float* __restrict__ M2,
    const float* __restrict__ bn0g, const float* __restrict__ bn0b,
    const float* __restrict__ w1, const float* __restrict__ b1,
    const float* __restrict__ bn1g, const float* __restrict__ bn1b,
    float* __restrict__ Wf, float* __restrict__ bf)
{
    __shared__ float sm[13], ss[13], st[13], scov[169];
    const float invN = 1.0f / (float)NPTS;
    int t = threadIdx.x;
    if (t < 13) {
        float m = sumF[t] * invN;
        int dd = t * 13 - t * (t - 1) / 2;   // tri index of (t,t)
        float var = M2[dd] * invN - m * m;
        float s = bn0g[t] * rsqrtf(var + EPSV);
        sm[t] = m; ss[t] = s; st[t] = bn0b[t] - m * s;
    }
    __syncthreads();
    for (int idx = t; idx < 169; idx += blockDim.x) {
        int j = idx / 13, l = idx % 13;
        int a = j < l ? j : l, b = j < l ? l : j;
        int tri = a * 13 - a * (a - 1) / 2 + (b - a);
        scov[idx] = M2[tri] * invN - sm[j] * sm[l];
    }
    __syncthreads();

    int k = t;  // 64 threads
    float w1p[13];
    float b1p = b1[k];
#pragma unroll
    for (int j = 0; j < 13; j++) {
        float w = w1[j * 64 + k];
        w1p[j] = ss[j] * w;
        b1p += st[j] * w;
    }
    float mean1 = b1p;
#pragma unroll
    for (int j = 0; j < 13; j++) mean1 += sm[j] * w1p[j];
    float var1 = 0.f;
    for (int j = 0; j < 13; j++)
        for (int l = 0; l < 13; l++)
            var1 += w1p[j] * w1p[l] * scov[j * 13 + l];
    float s1 = bn1g[k] * rsqrtf(var1 + EPSV);
    float t1 = bn1b[k] - mean1 * s1;
#pragma unroll
    for (int j = 0; j < 13; j++) Wf[j * 64 + k] = w1p[j] * s1;
    bf[k] = b1p * s1 + t1;
}

// ---------------- K4: main pass 1 — h2 column stats ----------------
__global__ __launch_bounds__(256, 2) void k4_stats2(
    const float4* __restrict__ pts, const float* __restrict__ nor,
    const int* __restrict__ gind, const int* __restrict__ cinv,
    const float4* __restrict__ vox4,
    const float* __restrict__ Wf, const float* __restrict__ bfv,
    const float* __restrict__ w2, const float* __restrict__ b2,
    float* __restrict__ sumH, float* __restrict__ sumQ)
{
    int lane = threadIdx.x & 63;
    int wsub = __builtin_amdgcn_readfirstlane((int)(threadIdx.x >> 6));
    int wid = blockIdx.x * 4 + wsub;
    int nw = gridDim.x * 4;

    float w1c[13];
#pragma unroll
    for (int j = 0; j < 13; j++) w1c[j] = Wf[j * 64 + lane];
    float b1c = bfv[lane];
    float w2c[64];
#pragma unroll
    for (int k = 0; k < 64; k++) w2c[k] = w2[k * 64 + lane];
    float b2c = b2[lane];

    float sh = 0.f, sq = 0.f;
    for (int p = wid; p < NPTS; p += nw) {
        float4 pt = pts[p];
        int v = cinv[p];
        float4 vs = vox4[v];
        float ic = 1.0f / fmaxf(vs.w, 1.0f);
        float gx = (float)gind[3 * p + 0];
        float gy = (float)gind[3 * p + 1];
        float gz = (float)gind[3 * p + 2];
        float f[13];
        f[0] = pt.x; f[1] = pt.y; f[2] = pt.z; f[3] = pt.w;
        f[4] = pt.x - vs.x * ic;
        f[5] = pt.y - vs.y * ic;
        f[6] = pt.z - vs.z * ic;
        f[7] = pt.x - (gx * 0.2f - 51.2f);
        f[8] = pt.y - (gy * 0.2f - 51.2f);
        f[9] = pt.z - (gz * 0.2f - 4.0f);
        f[10] = nor[3 * p + 0]; f[11] = nor[3 * p + 1]; f[12] = nor[3 * p + 2];

        float a0 = b1c, a1 = 0.f;
#pragma unroll
        for (int j = 0; j < 13; j += 2) a0 += f[j] * w1c[j];
#pragma unroll
        for (int j = 1; j < 13; j += 2) a1 += f[j] * w1c[j];
        float r = fmaxf(a0 + a1, 0.f);

        float h0 = b2c, h1 = 0.f, h2 = 0.f, h3 = 0.f;
#pragma unroll
        for (int k = 0; k < 64; k += 4) {
            h0 += bcast(r, k + 0) * w2c[k + 0];
            h1 += bcast(r, k + 1) * w2c[k + 1];
            h2 += bcast(r, k + 2) * w2c[k + 2];
            h3 += bcast(r, k + 3) * w2c[k + 3];
        }
        float h = (h0 + h1) + (h2 + h3);
        sh += h; sq += h * h;
    }
    atomicAdd(&sumH[lane], sh);
    atomicAdd(&sumQ[lane], sq);
}

// ---------------- K5: finalize BN2 -> s2, t2 ----------------
__global__ void k5_bn2(
    const float* __restrict__ sumH, const float* __restrict__ sumQ,
    const float* __restrict__ bn2g, const float* __restrict__ bn2b,
    float* __restrict__ s2, float* __restrict__ t2)
{
    const float invN = 1.0f / (float)NPTS;
    int c = threadIdx.x;
    float m = sumH[c] * invN;
    float var = sumQ[c] * invN - m * m;
    float s = bn2g[c] * rsqrtf(var + EPSV);
    s2[c] = s; t2[c] = bn2b[c] - m * s;
}

// ---------------- K6: main pass 2 — recompute h2, relu2, scatter-add ----------------
__global__ __launch_bounds__(256, 2) void k6_scatter(
    const float4* __restrict__ pts, const float* __restrict__ nor,
    const int* __restrict__ gind, const int* __restrict__ cinv,
    const float4* __restrict__ vox4,
    const float* __restrict__ Wf, const float* __restrict__ bfv,
    const float* __restrict__ w2, const float* __restrict__ b2,
    const float* __restrict__ s2, const float* __restrict__ t2,
    float* __restrict__ out)
{
    int lane = threadIdx.x & 63;
    int wsub = __builtin_amdgcn_readfirstlane((int)(threadIdx.x >> 6));
    int wid = blockIdx.x * 4 + wsub;
    int nw = gridDim.x * 4;

    float w1c[13];
#pragma unroll
    for (int j = 0; j < 13; j++) w1c[j] = Wf[j * 64 + lane];
    float b1c = bfv[lane];
    float w2c[64];
#pragma unroll
    for (int k = 0; k < 64; k++) w2c[k] = w2[k * 64 + lane];
    float b2c = b2[lane];
    float s2c = s2[lane], t2c = t2[lane];

    for (int p = wid; p < NPTS; p += nw) {
        float4 pt = pts[p];
        int v = cinv[p];
        float4 vs = vox4[v];
        float ic = 1.0f / fmaxf(vs.w, 1.0f);
        float gx = (float)gind[3 * p + 0];
        float gy = (float)gind[3 * p + 1];
        float gz = (float)gind[3 * p + 2];
        float f[13];
        f[0] = pt.x; f[1] = pt.y; f[2] = pt.z; f[3] = pt.w;
        f[4] = pt.x - vs.x * ic;
        f[5] = pt.y - vs.y * ic;
        f[6] = pt.z - vs.z * ic;
        f[7] = pt.x - (gx * 0.2f - 51.2f);
        f[8] = pt.y - (gy * 0.2f - 51.2f);
        f[9] = pt.z - (gz * 0.2f - 4.0f);
        f[10] = nor[3 * p + 0]; f[11] = nor[3 * p + 1]; f[12] = nor[3 * p + 2];

        float a0 = b1c, a1 = 0.f;
#pragma unroll
        for (int j = 0; j < 13; j += 2) a0 += f[j] * w1c[j];
#pragma unroll
        for (int j = 1; j < 13; j += 2) a1 += f[j] * w1c[j];
        float r = fmaxf(a0 + a1, 0.f);

        float h0 = b2c, h1 = 0.f, h2 = 0.f, h3 = 0.f;
#pragma unroll
        for (int k = 0; k < 64; k += 4) {
            h0 += bcast(r, k + 0) * w2c[k + 0];
            h1 += bcast(r, k + 1) * w2c[k + 1];
            h2 += bcast(r, k + 2) * w2c[k + 2];
            h3 += bcast(r, k + 3) * w2c[k + 3];
        }
        float h = (h0 + h1) + (h2 + h3);
        float z = fmaxf(s2c * h + t2c, 0.f);
        atomicAdd(&out[(size_t)v * 64 + lane], z);
    }
}

// ---------------- K7: per-voxel mean + matmul w3 + bias (in-place on d_out) ----------------
__global__ __launch_bounds__(256, 2) void k7_final(
    const float* __restrict__ vox, const float* __restrict__ w3,
    const float* __restrict__ b3, float* __restrict__ out)
{
    int lane = threadIdx.x & 63;
    int wsub = __builtin_amdgcn_readfirstlane((int)(threadIdx.x >> 6));
    int wid = blockIdx.x * 4 + wsub;
    int nw = gridDim.x * 4;

    float w3c[64];
#pragma unroll
    for (int c = 0; c < 64; c++) w3c[c] = w3[c * 64 + lane];
    float b3c = b3[lane];

    for (int v = wid; v < NVOX; v += nw) {
        float cnt = vox[v * 4 + 3];
        float* row = out + (size_t)v * 64;
        if (cnt > 0.5f) {
            float m = row[lane] / cnt;
            float a0 = b3c, a1 = 0.f, a2 = 0.f, a3 = 0.f;
#pragma unroll
            for (int c = 0; c < 64; c += 4) {
                a0 += bcast(m, c + 0) * w3c[c + 0];
                a1 += bcast(m, c + 1) * w3c[c + 1];
                a2 += bcast(m, c + 2) * w3c[c + 2];
                a3 += bcast(m, c + 3) * w3c[c + 3];
            }
            row[lane] = (a0 + a1) + (a2 + a3);
        } else {
            row[lane] = 0.f;
        }
    }
}

extern "C" void kernel_launch(void* const* d_in, const int* in_sizes, int n_in,
                              void* d_out, int out_size, void* d_ws, size_t ws_size,
                              hipStream_t stream) {
    const float4* pts  = (const float4*)d_in[0];
    const float*  nor  = (const float*)d_in[1];
    const int*    gind = (const int*)d_in[2];
    const int*    cinv = (const int*)d_in[3];
    const float*  bn0g = (const float*)d_in[4];
    const float*  bn0b = (const float*)d_in[5];
    const float*  w1   = (const float*)d_in[6];
    const float*  b1   = (const float*)d_in[7];
    const float*  bn1g = (const float*)d_in[8];
    const float*  bn1b = (const float*)d_in[9];
    const float*  w2   = (const float*)d_in[10];
    const float*  b2   = (const float*)d_in[11];
    const float*  bn2g = (const float*)d_in[12];
    const float*  bn2b = (const float*)d_in[13];
    const float*  w3   = (const float*)d_in[14];
    const float*  b3   = (const float*)d_in[15];

    float* ws   = (float*)d_ws;
    float* out  = (float*)d_out;
    float* vox  = ws;
    float* sumF = ws + OFF_SUMF;
    float* M2   = ws + OFF_M2;
    float* Wf   = ws + OFF_WF;
    float* bf   = ws + OFF_BF;
    float* sumH = ws + OFF_SUMH;
    float* sumQ = ws + OFF_SUMQ;
    float* s2   = ws + OFF_S2;
    float* t2   = ws + OFF_T2;

    hipMemsetAsync(d_ws, 0, (size_t)WS_FLOATS * sizeof(float), stream);
    hipMemsetAsync(d_out, 0, (size_t)NVOX * 64 * sizeof(float), stream);

    k1_scatter_xyz<<<(NPTS + 255) / 256, 256, 0, stream>>>(pts, cinv, vox);
    k2_stats0<<<1024, 256, 0, stream>>>(pts, nor, gind, cinv, (const float4*)vox, sumF, M2);
    k3_fold<<<1, 64, 0, stream>>>(sumF, M2, bn0g, bn0b, w1, b1, bn1g, bn1b, Wf, bf);
    k4_stats2<<<2048, 256, 0, stream>>>(pts, nor, gind, cinv, (const float4*)vox,
                                        Wf, bf, w2, b2, sumH, sumQ);
    k5_bn2<<<1, 64, 0, stream>>>(sumH, sumQ, bn2g, bn2b, s2, t2);
    k6_scatter<<<2048, 256, 0, stream>>>(pts, nor, gind, cinv, (const float4*)vox,
                                         Wf, bf, w2, b2, s2, t2, out);
    k7_final<<<512, 256, 0, stream>>>(vox, w3, b3, out);
}

// Round 3
// 1697.662 us; speedup vs baseline: 1.7664x; 1.7664x over previous
//
#include <hip/hip_runtime.h>

#define NPTS 1000000
#define NVOX 200000
#define EPSV 1e-5f

// ws layout (floats) — [0, ZERO_FLOATS) is memset to 0 each launch:
#define OFF_VOX   0          // 800000: per-voxel {sx,sy,sz,count}
#define OFF_SUMF  800000     // 13
#define OFF_M2    800013     // 91 (upper-tri second moments)
#define OFF_SUMH  800104     // 64
#define OFF_SUMQ  800168     // 64
#define OFF_CURS  800232     // 200000 (int cursor, zeroed)
#define ZERO_FLOATS 1000232
#define OFF_WF    1000232    // 832 (folded BN0+w1+BN1)
#define OFF_BF    1001064    // 64
#define OFF_S2    1001128    // 64
#define OFF_T2    1001192    // 64
#define OFF_PBASE 1001256    // 200000 (int, per-block-exclusive scan)
#define OFF_BSUM  1201256    // 512 (int, block sums)
#define OFF_BOFF  1201768    // 512 (int, scanned block sums)
#define OFF_BASE  1202280    // 200000 (int, CSR row starts)
#define OFF_PIDX  1402280    // 1000000 (int, CSR point indices)
#define WS_FLOATS 2402280

#define SCAN_B 512
#define NSCAN ((NVOX + SCAN_B - 1) / SCAN_B)   // 391

__device__ __forceinline__ float bcast(float x, int k) {
    return __int_as_float(__builtin_amdgcn_readlane(__float_as_int(x), k));
}

// ---- compile-time triangular index math (13x13 upper tri, 91 entries) ----
constexpr int tri_jf(int t) {
    int j = 0, rs = 0;
    while (rs + (13 - j) <= t) { rs += 13 - j; ++j; }
    return j;
}
constexpr int tri_lf(int t) {
    int j = tri_jf(t);
    int rs = 13 * j - j * (j - 1) / 2;
    return j + (t - rs);
}

// Template-recursive accumulators: EVERY array index is a compile-time
// constant, so SROA promotes to VGPRs (R1/R2's loop-carried idx defeated
// promotion -> full scratch spill, k2 at 578/1824us with 1% VALUBusy).
template<int T, int CNT, int BASE>
struct Mom {
    static __device__ __forceinline__ void init(float (&a)[CNT]) {
        a[T] = 0.f; Mom<T + 1, CNT, BASE>::init(a);
    }
    static __device__ __forceinline__ void acc(float (&a)[CNT], const float (&f)[13]) {
        constexpr int J = tri_jf(BASE + T);
        constexpr int L = tri_lf(BASE + T);
        a[T] += f[J] * f[L];
        Mom<T + 1, CNT, BASE>::acc(a, f);
    }
    static __device__ __forceinline__ void red(float (&a)[CNT], float* M2, int lane) {
        float x = a[T];
#pragma unroll
        for (int o = 32; o > 0; o >>= 1) x += __shfl_down(x, o);
        if (lane == 0) atomicAdd(&M2[BASE + T], x);
        Mom<T + 1, CNT, BASE>::red(a, M2, lane);
    }
};
template<int CNT, int BASE>
struct Mom<CNT, CNT, BASE> {
    static __device__ __forceinline__ void init(float (&)[CNT]) {}
    static __device__ __forceinline__ void acc(float (&)[CNT], const float (&)[13]) {}
    static __device__ __forceinline__ void red(float (&)[CNT], float*, int) {}
};

template<int T>
struct SF13 {
    static __device__ __forceinline__ void init(float (&a)[13]) {
        a[T] = 0.f; SF13<T + 1>::init(a);
    }
    static __device__ __forceinline__ void acc(float (&a)[13], const float (&f)[13]) {
        a[T] += f[T]; SF13<T + 1>::acc(a, f);
    }
    static __device__ __forceinline__ void red(float (&a)[13], float* dst, int lane) {
        float x = a[T];
#pragma unroll
        for (int o = 32; o > 0; o >>= 1) x += __shfl_down(x, o);
        if (lane == 0) atomicAdd(&dst[T], x);
        SF13<T + 1>::red(a, dst, lane);
    }
};
template<> struct SF13<13> {
    static __device__ __forceinline__ void init(float (&)[13]) {}
    static __device__ __forceinline__ void acc(float (&)[13], const float (&)[13]) {}
    static __device__ __forceinline__ void red(float (&)[13], float*, int) {}
};

__device__ __forceinline__ void build_features(
    const float4* __restrict__ pts, const float* __restrict__ nor,
    const int* __restrict__ gind, const int* __restrict__ cinv,
    const float4* __restrict__ vox4, int i, float (&f)[13])
{
    float4 p = pts[i];
    int v = cinv[i];
    float4 vs = vox4[v];
    float ic = 1.0f / fmaxf(vs.w, 1.0f);
    f[0] = p.x; f[1] = p.y; f[2] = p.z; f[3] = p.w;
    f[4] = p.x - vs.x * ic;
    f[5] = p.y - vs.y * ic;
    f[6] = p.z - vs.z * ic;
    f[7] = p.x - ((float)gind[3 * i + 0] * 0.2f - 51.2f);
    f[8] = p.y - ((float)gind[3 * i + 1] * 0.2f - 51.2f);
    f[9] = p.z - ((float)gind[3 * i + 2] * 0.2f - 4.0f);
    f[10] = nor[3 * i + 0]; f[11] = nor[3 * i + 1]; f[12] = nor[3 * i + 2];
}

// ---------------- K1: scatter xyz sums + counts per voxel ----------------
__global__ __launch_bounds__(256) void k1_scatter_xyz(
    const float4* __restrict__ pts, const int* __restrict__ cinv,
    float* __restrict__ vox)
{
    int i = blockIdx.x * blockDim.x + threadIdx.x;
    if (i >= NPTS) return;
    float4 p = pts[i];
    int v = cinv[i];
    atomicAdd(&vox[v * 4 + 0], p.x);
    atomicAdd(&vox[v * 4 + 1], p.y);
    atomicAdd(&vox[v * 4 + 2], p.z);
    atomicAdd(&vox[v * 4 + 3], 1.0f);
}

// ---------------- K2: moments, 2-color split (rows 0..3 | rows 4..12) ----
template<int BASE, int CNT, bool DO_SF>
__device__ __forceinline__ void k2_body(
    const float4* __restrict__ pts, const float* __restrict__ nor,
    const int* __restrict__ gind, const int* __restrict__ cinv,
    const float4* __restrict__ vox4,
    float* __restrict__ sumF, float* __restrict__ M2, int tid, int T)
{
    float m2a[CNT];
    Mom<0, CNT, BASE>::init(m2a);
    float sfa[13];
    SF13<0>::init(sfa);

    for (int i = tid; i < NPTS; i += T) {
        float f[13];
        build_features(pts, nor, gind, cinv, vox4, i, f);
        Mom<0, CNT, BASE>::acc(m2a, f);
        if (DO_SF) SF13<0>::acc(sfa, f);
    }
    int lane = threadIdx.x & 63;
    Mom<0, CNT, BASE>::red(m2a, M2, lane);
    if (DO_SF) SF13<0>::red(sfa, sumF, lane);
}

__global__ __launch_bounds__(256, 2) void k2_stats0(
    const float4* __restrict__ pts, const float* __restrict__ nor,
    const int* __restrict__ gind, const int* __restrict__ cinv,
    const float4* __restrict__ vox4,
    float* __restrict__ sumF, float* __restrict__ M2)
{
    int color = blockIdx.x & 1;
    int tid = (blockIdx.x >> 1) * blockDim.x + threadIdx.x;
    int T = (gridDim.x >> 1) * blockDim.x;
    if (color == 0)
        k2_body<0, 46, true>(pts, nor, gind, cinv, vox4, sumF, M2, tid, T);
    else
        k2_body<46, 45, false>(pts, nor, gind, cinv, vox4, sumF, M2, tid, T);
}

// ---------------- K3: fold BN0 + w1 + BN1 into Wf, bf ----------------
__global__ void k3_fold(
    const float* __restrict__ sumF, const float* __restrict__ M2,
    const float* __restrict__ bn0g, const float* __restrict__ bn0b,
    const float* __restrict__ w1, const float* __restrict__ b1,
    const float* __restrict__ bn1g, const float* __restrict__ bn1b,
    float* __restrict__ Wf, float* __restrict__ bf)
{
    __shared__ float sm[13], ss[13], st[13], scov[169];
    const float invN = 1.0f / (float)NPTS;
    int t = threadIdx.x;
    if (t < 13) {
        float m = sumF[t] * invN;
        int dd = t * 13 - t * (t - 1) / 2;
        float var = M2[dd] * invN - m * m;
        float s = bn0g[t] * rsqrtf(var + EPSV);
        sm[t] = m; ss[t] = s; st[t] = bn0b[t] - m * s;
    }
    __syncthreads();
    for (int idx = t; idx < 169; idx += blockDim.x) {
        int j = idx / 13, l = idx % 13;
        int a = j < l ? j : l, b = j < l ? l : j;
        int tri = a * 13 - a * (a - 1) / 2 + (b - a);
        scov[idx] = M2[tri] * invN - sm[j] * sm[l];
    }
    __syncthreads();

    int k = t;  // 64 threads
    float w1p[13];
    float b1p = b1[k];
#pragma unroll
    for (int j = 0; j < 13; j++) {
        float w = w1[j * 64 + k];
        w1p[j] = ss[j] * w;
        b1p += st[j] * w;
    }
    float mean1 = b1p;
#pragma unroll
    for (int j = 0; j < 13; j++) mean1 += sm[j] * w1p[j];
    float var1 = 0.f;
    for (int j = 0; j < 13; j++)
        for (int l = 0; l < 13; l++)
            var1 += w1p[j] * w1p[l] * scov[j * 13 + l];
    float s1 = bn1g[k] * rsqrtf(var1 + EPSV);
    float t1 = bn1b[k] - mean1 * s1;
#pragma unroll
    for (int j = 0; j < 13; j++) Wf[j * 64 + k] = w1p[j] * s1;
    bf[k] = b1p * s1 + t1;
}

// ---------------- CSR build: scan counts, fill point indices ----------------
__global__ __launch_bounds__(SCAN_B) void k_scan1(
    const float* __restrict__ vox, int* __restrict__ pbase, int* __restrict__ bsum)
{
    __shared__ int sd[SCAN_B];
    int t = threadIdx.x;
    int v = blockIdx.x * SCAN_B + t;
    int x = (v < NVOX) ? (int)vox[4 * v + 3] : 0;
    sd[t] = x;
    __syncthreads();
    for (int o = 1; o < SCAN_B; o <<= 1) {
        int y = (t >= o) ? sd[t - o] : 0;
        __syncthreads();
        sd[t] += y;
        __syncthreads();
    }
    if (v < NVOX) pbase[v] = sd[t] - x;
    if (t == SCAN_B - 1) bsum[blockIdx.x] = sd[t];
}

__global__ __launch_bounds__(SCAN_B) void k_scan2(
    const int* __restrict__ bsum, int* __restrict__ boff)
{
    __shared__ int sd[SCAN_B];
    int t = threadIdx.x;
    int x = (t < NSCAN) ? bsum[t] : 0;
    sd[t] = x;
    __syncthreads();
    for (int o = 1; o < SCAN_B; o <<= 1) {
        int y = (t >= o) ? sd[t - o] : 0;
        __syncthreads();
        sd[t] += y;
        __syncthreads();
    }
    if (t < NSCAN) boff[t] = sd[t] - x;
}

__global__ __launch_bounds__(256) void k_base(
    const int* __restrict__ pbase, const int* __restrict__ boff, int* __restrict__ base)
{
    int v = blockIdx.x * 256 + threadIdx.x;
    if (v < NVOX) base[v] = pbase[v] + boff[v >> 9];
}

__global__ __launch_bounds__(256) void k_fill(
    const int* __restrict__ cinv, const int* __restrict__ base,
    int* __restrict__ cursor, int* __restrict__ pidx)
{
    int i = blockIdx.x * 256 + threadIdx.x;
    if (i >= NPTS) return;
    int v = cinv[i];
    int slot = base[v] + atomicAdd(&cursor[v], 1);
    pidx[slot] = i;
}

// ---------------- K4: main pass 1 — h2 column stats ----------------
__global__ __launch_bounds__(256, 2) void k4_stats2(
    const float4* __restrict__ pts, const float* __restrict__ nor,
    const int* __restrict__ gind, const int* __restrict__ cinv,
    const float4* __restrict__ vox4,
    const float* __restrict__ Wf, const float* __restrict__ bfv,
    const float* __restrict__ w2, const float* __restrict__ b2,
    float* __restrict__ sumH, float* __restrict__ sumQ)
{
    int lane = threadIdx.x & 63;
    int wsub = __builtin_amdgcn_readfirstlane((int)(threadIdx.x >> 6));
    int wid = blockIdx.x * 4 + wsub;
    int nw = gridDim.x * 4;

    float w1c[13];
#pragma unroll
    for (int j = 0; j < 13; j++) w1c[j] = Wf[j * 64 + lane];
    float b1c = bfv[lane];
    float w2c[64];
#pragma unroll
    for (int k = 0; k < 64; k++) w2c[k] = w2[k * 64 + lane];
    float b2c = b2[lane];

    float sh = 0.f, sq = 0.f;
    for (int p = wid; p < NPTS; p += nw) {
        float f[13];
        build_features(pts, nor, gind, cinv, vox4, p, f);

        float a0 = b1c, a1 = 0.f;
#pragma unroll
        for (int j = 0; j < 13; j += 2) a0 += f[j] * w1c[j];
#pragma unroll
        for (int j = 1; j < 13; j += 2) a1 += f[j] * w1c[j];
        float r = fmaxf(a0 + a1, 0.f);

        float h0 = b2c, h1 = 0.f, h2 = 0.f, h3 = 0.f;
#pragma unroll
        for (int k = 0; k < 64; k += 4) {
            h0 += bcast(r, k + 0) * w2c[k + 0];
            h1 += bcast(r, k + 1) * w2c[k + 1];
            h2 += bcast(r, k + 2) * w2c[k + 2];
            h3 += bcast(r, k + 3) * w2c[k + 3];
        }
        float h = (h0 + h1) + (h2 + h3);
        sh += h; sq += h * h;
    }
    atomicAdd(&sumH[lane], sh);
    atomicAdd(&sumQ[lane], sq);
}

// ---------------- K5: finalize BN2 -> s2, t2 ----------------
__global__ void k5_bn2(
    const float* __restrict__ sumH, const float* __restrict__ sumQ,
    const float* __restrict__ bn2g, const float* __restrict__ bn2b,
    float* __restrict__ s2, float* __restrict__ t2)
{
    const float invN = 1.0f / (float)NPTS;
    int c = threadIdx.x;
    float m = sumH[c] * invN;
    float var = sumQ[c] * invN - m * m;
    float s = bn2g[c] * rsqrtf(var + EPSV);
    s2[c] = s; t2[c] = bn2b[c] - m * s;
}

// ---------------- K6: per-voxel gather via CSR, plain store (no atomics) ----
__global__ __launch_bounds__(256, 2) void k6_gather(
    const float4* __restrict__ pts, const float* __restrict__ nor,
    const int* __restrict__ gind,
    const float4* __restrict__ vox4,
    const float* __restrict__ Wf, const float* __restrict__ bfv,
    const float* __restrict__ w2, const float* __restrict__ b2,
    const float* __restrict__ s2, const float* __restrict__ t2,
    const int* __restrict__ base, const int* __restrict__ pidx,
    float* __restrict__ out)
{
    int lane = threadIdx.x & 63;
    int wsub = __builtin_amdgcn_readfirstlane((int)(threadIdx.x >> 6));
    int wid = blockIdx.x * 4 + wsub;
    int nw = gridDim.x * 4;

    float w1c[13];
#pragma unroll
    for (int j = 0; j < 13; j++) w1c[j] = Wf[j * 64 + lane];
    float b1c = bfv[lane];
    float w2c[64];
#pragma unroll
    for (int k = 0; k < 64; k++) w2c[k] = w2[k * 64 + lane];
    float b2c = b2[lane];
    float s2c = s2[lane], t2c = t2[lane];

    for (int v = wid; v < NVOX; v += nw) {
        float4 vs = vox4[v];
        int n = (int)vs.w;
        int st = base[v];
        float ic = 1.0f / fmaxf(vs.w, 1.0f);
        float mx = vs.x * ic, my = vs.y * ic, mz = vs.z * ic;

        float accz = 0.f;
        for (int i = 0; i < n; i++) {
            int p = pidx[st + i];
            float4 pt = pts[p];
            float f[13];
            f[0] = pt.x; f[1] = pt.y; f[2] = pt.z; f[3] = pt.w;
            f[4] = pt.x - mx; f[5] = pt.y - my; f[6] = pt.z - mz;
            f[7] = pt.x - ((float)gind[3 * p + 0] * 0.2f - 51.2f);
            f[8] = pt.y - ((float)gind[3 * p + 1] * 0.2f - 51.2f);
            f[9] = pt.z - ((float)gind[3 * p + 2] * 0.2f - 4.0f);
            f[10] = nor[3 * p + 0]; f[11] = nor[3 * p + 1]; f[12] = nor[3 * p + 2];

            float a0 = b1c, a1 = 0.f;
#pragma unroll
            for (int j = 0; j < 13; j += 2) a0 += f[j] * w1c[j];
#pragma unroll
            for (int j = 1; j < 13; j += 2) a1 += f[j] * w1c[j];
            float r = fmaxf(a0 + a1, 0.f);

            float h0 = b2c, h1 = 0.f, h2 = 0.f, h3 = 0.f;
#pragma unroll
            for (int k = 0; k < 64; k += 4) {
                h0 += bcast(r, k + 0) * w2c[k + 0];
                h1 += bcast(r, k + 1) * w2c[k + 1];
                h2 += bcast(r, k + 2) * w2c[k + 2];
                h3 += bcast(r, k + 3) * w2c[k + 3];
            }
            float h = (h0 + h1) + (h2 + h3);
            accz += fmaxf(s2c * h + t2c, 0.f);
        }
        out[(size_t)v * 64 + lane] = accz;
    }
}

// ---------------- K7: per-voxel mean + matmul w3 + bias (in-place) ----------
__global__ __launch_bounds__(256, 2) void k7_final(
    const float* __restrict__ vox, const float* __restrict__ w3,
    const float* __restrict__ b3, float* __restrict__ out)
{
    int lane = threadIdx.x & 63;
    int wsub = __builtin_amdgcn_readfirstlane((int)(threadIdx.x >> 6));
    int wid = blockIdx.x * 4 + wsub;
    int nw = gridDim.x * 4;

    float w3c[64];
#pragma unroll
    for (int c = 0; c < 64; c++) w3c[c] = w3[c * 64 + lane];
    float b3c = b3[lane];

    for (int v = wid; v < NVOX; v += nw) {
        float cnt = vox[v * 4 + 3];
        float* row = out + (size_t)v * 64;
        if (cnt > 0.5f) {
            float m = row[lane] / cnt;
            float a0 = b3c, a1 = 0.f, a2 = 0.f, a3 = 0.f;
#pragma unroll
            for (int c = 0; c < 64; c += 4) {
                a0 += bcast(m, c + 0) * w3c[c + 0];
                a1 += bcast(m, c + 1) * w3c[c + 1];
                a2 += bcast(m, c + 2) * w3c[c + 2];
                a3 += bcast(m, c + 3) * w3c[c + 3];
            }
            row[lane] = (a0 + a1) + (a2 + a3);
        } else {
            row[lane] = 0.f;
        }
    }
}

extern "C" void kernel_launch(void* const* d_in, const int* in_sizes, int n_in,
                              void* d_out, int out_size, void* d_ws, size_t ws_size,
                              hipStream_t stream) {
    const float4* pts  = (const float4*)d_in[0];
    const float*  nor  = (const float*)d_in[1];
    const int*    gind = (const int*)d_in[2];
    const int*    cinv = (const int*)d_in[3];
    const float*  bn0g = (const float*)d_in[4];
    const float*  bn0b = (const float*)d_in[5];
    const float*  w1   = (const float*)d_in[6];
    const float*  b1   = (const float*)d_in[7];
    const float*  bn1g = (const float*)d_in[8];
    const float*  bn1b = (const float*)d_in[9];
    const float*  w2   = (const float*)d_in[10];
    const float*  b2   = (const float*)d_in[11];
    const float*  bn2g = (const float*)d_in[12];
    const float*  bn2b = (const float*)d_in[13];
    const float*  w3   = (const float*)d_in[14];
    const float*  b3   = (const float*)d_in[15];

    float* ws   = (float*)d_ws;
    float* out  = (float*)d_out;
    float* vox  = ws + OFF_VOX;
    float* sumF = ws + OFF_SUMF;
    float* M2   = ws + OFF_M2;
    float* sumH = ws + OFF_SUMH;
    float* sumQ = ws + OFF_SUMQ;
    int*   curs = (int*)(ws + OFF_CURS);
    float* Wf   = ws + OFF_WF;
    float* bf   = ws + OFF_BF;
    float* s2   = ws + OFF_S2;
    float* t2   = ws + OFF_T2;
    int*   pbase = (int*)(ws + OFF_PBASE);
    int*   bsum  = (int*)(ws + OFF_BSUM);
    int*   boff  = (int*)(ws + OFF_BOFF);
    int*   base  = (int*)(ws + OFF_BASE);
    int*   pidx  = (int*)(ws + OFF_PIDX);

    hipMemsetAsync(d_ws, 0, (size_t)ZERO_FLOATS * sizeof(float), stream);

    k1_scatter_xyz<<<(NPTS + 255) / 256, 256, 0, stream>>>(pts, cinv, vox);
    k2_stats0<<<512, 256, 0, stream>>>(pts, nor, gind, cinv, (const float4*)vox, sumF, M2);
    k3_fold<<<1, 64, 0, stream>>>(sumF, M2, bn0g, bn0b, w1, b1, bn1g, bn1b, Wf, bf);

    k_scan1<<<NSCAN, SCAN_B, 0, stream>>>(vox, pbase, bsum);
    k_scan2<<<1, SCAN_B, 0, stream>>>(bsum, boff);
    k_base<<<(NVOX + 255) / 256, 256, 0, stream>>>(pbase, boff, base);
    k_fill<<<(NPTS + 255) / 256, 256, 0, stream>>>(cinv, base, curs, pidx);

    k4_stats2<<<2048, 256, 0, stream>>>(pts, nor, gind, cinv, (const float4*)vox,
                                        Wf, bf, w2, b2, sumH, sumQ);
    k5_bn2<<<1, 64, 0, stream>>>(sumH, sumQ, bn2g, bn2b, s2, t2);
    k6_gather<<<4096, 256, 0, stream>>>(pts, nor, gind, (const float4*)vox,
                                        Wf, bf, w2, b2, s2, t2, base, pidx, out);
    k7_final<<<512, 256, 0, stream>>>(vox, w3, b3, out);
}